// Round 8
// baseline (122.755 us; speedup 1.0000x reference)
//
#include <hip/hip_runtime.h>
#include <math.h>
#include <float.h>

// Problem constants (from the reference)
#define NN 4096
#define DD 512
#define PP 8
#define QQ 32
#define NB_TOT 40
#define NPW 8                      // neighbors per wave (5 waves x 8 = 40)
constexpr float MARGIN = 1.0f;
constexpr float L2W    = 0.005f;
constexpr float EPS    = 1e-6f;

typedef _Float16 half8 __attribute__((ext_vector_type(8)));

// ws layout (floats):
//   [0, NN*DD/2)             fp16 batch copy (4 MB, NN*DD halves)
//   [NN*DD/2, +NN)           per-row fp32 norms
#define WS_NORM (NN * DD / 2)

__device__ inline float wave_reduce_sum(float v) {
    v += __shfl_xor(v, 32, 64);
    v += __shfl_xor(v, 16, 64);
    v += __shfl_xor(v,  8, 64);
    v += __shfl_xor(v,  4, 64);
    v += __shfl_xor(v,  2, 64);
    v += __shfl_xor(v,  1, 64);
    return v;
}

__device__ inline float wave_reduce_max(float v) {
    v = fmaxf(v, __shfl_xor(v, 32, 64));
    v = fmaxf(v, __shfl_xor(v, 16, 64));
    v = fmaxf(v, __shfl_xor(v,  8, 64));
    v = fmaxf(v, __shfl_xor(v,  4, 64));
    v = fmaxf(v, __shfl_xor(v,  2, 64));
    v = fmaxf(v, __shfl_xor(v,  1, 64));
    return v;
}

// One wave per row: read 2KB fp32 (coalesced), write 1KB fp16 (coalesced),
// exact fp32 row norm. Also zeroes d_out (dist kernel accumulates into it).
__global__ __launch_bounds__(256) void convert_kernel(
    const float4* __restrict__ batch4,   // [NN*128]
    half8*        __restrict__ hb,       // [NN*64]
    float*        __restrict__ norms,    // [NN]
    float*        __restrict__ out)
{
    const int row  = blockIdx.x * 4 + (threadIdx.x >> 6);
    const int lane = threadIdx.x & 63;

    const float4 v0 = batch4[row * 128 + lane * 2];
    const float4 v1 = batch4[row * 128 + lane * 2 + 1];

    half8 h;
    h[0] = (_Float16)v0.x; h[1] = (_Float16)v0.y;
    h[2] = (_Float16)v0.z; h[3] = (_Float16)v0.w;
    h[4] = (_Float16)v1.x; h[5] = (_Float16)v1.y;
    h[6] = (_Float16)v1.z; h[7] = (_Float16)v1.w;
    hb[row * 64 + lane] = h;

    float s = v0.x*v0.x + v0.y*v0.y + v0.z*v0.z + v0.w*v0.w
            + v1.x*v1.x + v1.y*v1.y + v1.z*v1.z + v1.w*v1.w;
    s = wave_reduce_sum(s);
    if (lane == 0) norms[row] = sqrtf(s);
    if (blockIdx.x == 0 && threadIdx.x == 0) out[0] = 0.0f;
}

// One block per anchor; 5 waves x 8 neighbors. Each fp16 row is ONE dwordx4
// per wave (1 KB), 9 row-requests in flight, gathered from the 4 MB fp16
// batch (L2-resident per XCD). Cross-lane reduce uses the halving
// multi-reduce: 10 shuffles/wave for 8 neighbors (vs 48 naive).
// Epilogue fused; one atomicAdd per block.
__global__ __launch_bounds__(320) void dist_kernel(
    const half8* __restrict__ hb,
    const int*   __restrict__ anchors,
    const int*   __restrict__ pos_idx,
    const int*   __restrict__ neg_idx,
    const float* __restrict__ norms,
    float*       __restrict__ out)
{
    const int i    = blockIdx.x;
    const int tid  = threadIdx.x;
    const int lane = tid & 63;
    const int wave = tid >> 6;            // 0..4
    const int jb   = wave * NPW;          // 0,8,16,24,32

    __shared__ float dist[NB_TOT];

    // ---- anchor row (one request), fp32 + eps ----
    const int arow = anchors[i];
    const half8 ah = hb[(size_t)arow * 64 + lane];
    float a[8];
    #pragma unroll
    for (int k = 0; k < 8; ++k) a[k] = (float)ah[k] + EPS;

    // ---- this wave's 8 neighbor indices (wave-uniform scalar loads) ----
    int idxs[NPW];
    #pragma unroll
    for (int t = 0; t < NPW; ++t) {
        const int j = jb + t;
        idxs[t] = (j < PP) ? pos_idx[i * PP + j] : neg_idx[i * QQ + (j - PP)];
    }

    // ---- all 8 row requests in flight ----
    half8 bh[NPW];
    #pragma unroll
    for (int t = 0; t < NPW; ++t)
        bh[t] = hb[(size_t)idxs[t] * 64 + lane];

    // ---- squared distances in fp32 (per-lane partials) ----
    float s[NPW];
    #pragma unroll
    for (int t = 0; t < NPW; ++t) {
        float acc = 0.0f;
        #pragma unroll
        for (int k = 0; k < 8; ++k) {
            const float d = a[k] - (float)bh[t][k];
            acc = fmaf(d, d, acc);
        }
        s[t] = acc;
    }

    // ---- halving multi-reduce: 8 sums in 10 shuffles ----
    // step 1 (xor 32): bit5=0 lanes keep neighbors 0..3, bit5=1 keep 4..7
    float h4[4];
    #pragma unroll
    for (int t = 0; t < 4; ++t) {
        const bool hi = (lane & 32) != 0;
        const float send = hi ? s[t] : s[t + 4];
        const float recv = __shfl_xor(send, 32, 64);
        h4[t] = (hi ? s[t + 4] : s[t]) + recv;
    }
    // step 2 (xor 16): bit4 selects +2
    float h2[2];
    #pragma unroll
    for (int t = 0; t < 2; ++t) {
        const bool hi = (lane & 16) != 0;
        const float send = hi ? h4[t] : h4[t + 2];
        const float recv = __shfl_xor(send, 16, 64);
        h2[t] = (hi ? h4[t + 2] : h4[t]) + recv;
    }
    // step 3 (xor 8): bit3 selects +1
    float h1;
    {
        const bool hi = (lane & 8) != 0;
        const float send = hi ? h2[0] : h2[1];
        const float recv = __shfl_xor(send, 8, 64);
        h1 = (hi ? h2[1] : h2[0]) + recv;
    }
    // in-group butterfly (xor 4,2,1): all 8 lanes of group g = lane>>3 end
    // with the full sum of neighbor jb + g (g's bits = (b5,b4,b3) path).
    h1 += __shfl_xor(h1, 4, 64);
    h1 += __shfl_xor(h1, 2, 64);
    h1 += __shfl_xor(h1, 1, 64);

    if ((lane & 7) == 0) dist[jb + (lane >> 3)] = sqrtf(h1);

    __syncthreads();

    // ---- wave-parallel logsumexp epilogue (lanes 0..39 of wave 0) ----
    if (wave == 0) {
        const float d = (lane < NB_TOT) ? dist[lane] : 0.0f;

        const bool pact = (lane < PP);
        const float pm = wave_reduce_max(pact ? d : -FLT_MAX);
        const float ps = wave_reduce_sum(pact ? expf(d - pm) : 0.0f);
        const float pos_term = pm + logf(ps);

        const bool nact = (lane >= PP) && (lane < NB_TOT);
        const float nv = MARGIN - d;
        const float nm = wave_reduce_max(nact ? nv : -FLT_MAX);
        const float ns = wave_reduce_sum(nact ? expf(nv - nm) : 0.0f);
        const float neg_term = nm + logf(ns);

        if (lane == 0) {
            const float val = fmaxf(0.0f, pos_term + neg_term) + L2W * norms[i];
            atomicAdd(out, val * (1.0f / (float)NN));
        }
    }
}

extern "C" void kernel_launch(void* const* d_in, const int* in_sizes, int n_in,
                              void* d_out, int out_size, void* d_ws, size_t ws_size,
                              hipStream_t stream) {
    const float* batch   = (const float*)d_in[0];
    const int*   anchors = (const int*)d_in[1];
    const int*   pos_idx = (const int*)d_in[2];
    const int*   neg_idx = (const int*)d_in[3];
    float*       wsf     = (float*)d_ws;
    float*       out     = (float*)d_out;

    half8* hb    = (half8*)wsf;
    float* norms = wsf + WS_NORM;

    convert_kernel<<<NN / 4, 256, 0, stream>>>((const float4*)batch, hb, norms, out);
    dist_kernel<<<NN, 320, 0, stream>>>(hb, anchors, pos_idx, neg_idx, norms, out);
}